// Round 6
// baseline (679.075 us; speedup 1.0000x reference)
//
#include <hip/hip_runtime.h>

#define G      1024
#define NNODES 65536
#define NEDGES 262144
#define D      256
#define DIN    768
#define DHID   512
#define DOUT   256

#define NBLK   512                      // grid: capacity-safe (2 blocks/CU x 256 CUs)
#define GRP    32                       // graphs per m-group (GEMM TM = 32)
#define NGRP   (G / GRP)                // 32
#define G1_BLOCKS (NGRP * (DHID / 64))  // 256 GEMM1 tiles
#define G2_BLOCKS (NGRP * (DOUT / 64))  // 128 GEMM2 tiles

__device__ __forceinline__ int lower_bound(const int* __restrict__ a, int n, int key) {
    int lo = 0, hi = n;
    while (lo < hi) {
        const int mid = (lo + hi) >> 1;
        if (a[mid] < key) lo = mid + 1; else hi = mid;
    }
    return lo;
}

struct LdsRed { float se[4][D]; float sn[4][D]; };                 // 8 KB
struct LdsGemm { float At[2][32][34]; float Bs[2][32][64]; };      // 25 KB

// Aggregate one graph: stream-sum its contiguous row ranges (8 float4 in
// flight per wave), LDS-reduce the 4 waves, write collected[g].
__device__ __forceinline__ void aggregate_one(
        int g, const float4* __restrict__ nodes, const float4* __restrict__ edges,
        const float4* __restrict__ globals_, const int* __restrict__ nids,
        const int* __restrict__ eids, float* __restrict__ collected, LdsRed* red) {
    const int lane = threadIdx.x & 63;
    const int wave = threadIdx.x >> 6;

    const int es = lower_bound(eids, NEDGES, g);
    const int ee = lower_bound(eids, NEDGES, g + 1);
    const int ns = lower_bound(nids, NNODES, g);
    const int ne = lower_bound(nids, NNODES, g + 1);

    float4 acc_e = {0.f, 0.f, 0.f, 0.f};
    {
        int r = es + wave;
        for (; r + 28 < ee; r += 32) {
            const float4 v0 = edges[(size_t)(r +  0) * (D / 4) + lane];
            const float4 v1 = edges[(size_t)(r +  4) * (D / 4) + lane];
            const float4 v2 = edges[(size_t)(r +  8) * (D / 4) + lane];
            const float4 v3 = edges[(size_t)(r + 12) * (D / 4) + lane];
            const float4 v4 = edges[(size_t)(r + 16) * (D / 4) + lane];
            const float4 v5 = edges[(size_t)(r + 20) * (D / 4) + lane];
            const float4 v6 = edges[(size_t)(r + 24) * (D / 4) + lane];
            const float4 v7 = edges[(size_t)(r + 28) * (D / 4) + lane];
            acc_e.x += ((v0.x + v1.x) + (v2.x + v3.x)) + ((v4.x + v5.x) + (v6.x + v7.x));
            acc_e.y += ((v0.y + v1.y) + (v2.y + v3.y)) + ((v4.y + v5.y) + (v6.y + v7.y));
            acc_e.z += ((v0.z + v1.z) + (v2.z + v3.z)) + ((v4.z + v5.z) + (v6.z + v7.z));
            acc_e.w += ((v0.w + v1.w) + (v2.w + v3.w)) + ((v4.w + v5.w) + (v6.w + v7.w));
        }
        for (; r < ee; r += 4) {
            const float4 v = edges[(size_t)r * (D / 4) + lane];
            acc_e.x += v.x; acc_e.y += v.y; acc_e.z += v.z; acc_e.w += v.w;
        }
    }
    float4 acc_n = {0.f, 0.f, 0.f, 0.f};
    {
        int r = ns + wave;
        for (; r + 28 < ne; r += 32) {
            const float4 v0 = nodes[(size_t)(r +  0) * (D / 4) + lane];
            const float4 v1 = nodes[(size_t)(r +  4) * (D / 4) + lane];
            const float4 v2 = nodes[(size_t)(r +  8) * (D / 4) + lane];
            const float4 v3 = nodes[(size_t)(r + 12) * (D / 4) + lane];
            const float4 v4 = nodes[(size_t)(r + 16) * (D / 4) + lane];
            const float4 v5 = nodes[(size_t)(r + 20) * (D / 4) + lane];
            const float4 v6 = nodes[(size_t)(r + 24) * (D / 4) + lane];
            const float4 v7 = nodes[(size_t)(r + 28) * (D / 4) + lane];
            acc_n.x += ((v0.x + v1.x) + (v2.x + v3.x)) + ((v4.x + v5.x) + (v6.x + v7.x));
            acc_n.y += ((v0.y + v1.y) + (v2.y + v3.y)) + ((v4.y + v5.y) + (v6.y + v7.y));
            acc_n.z += ((v0.z + v1.z) + (v2.z + v3.z)) + ((v4.z + v5.z) + (v6.z + v7.z));
            acc_n.w += ((v0.w + v1.w) + (v2.w + v3.w)) + ((v4.w + v5.w) + (v6.w + v7.w));
        }
        for (; r < ne; r += 4) {
            const float4 v = nodes[(size_t)r * (D / 4) + lane];
            acc_n.x += v.x; acc_n.y += v.y; acc_n.z += v.z; acc_n.w += v.w;
        }
    }

    *(float4*)&red->se[wave][lane * 4] = acc_e;
    *(float4*)&red->sn[wave][lane * 4] = acc_n;
    __syncthreads();

    const int t = threadIdx.x;
    const float ev = (red->se[0][t] + red->se[1][t]) + (red->se[2][t] + red->se[3][t]);
    const float nv = (red->sn[0][t] + red->sn[1][t]) + (red->sn[2][t] + red->sn[3][t]);
    float* row = collected + (size_t)g * DIN;
    row[t]         = ev;
    row[D + t]     = nv;
    row[2 * D + t] = ((const float*)globals_)[(size_t)g * D + t];
}

// 32x64 fp32 GEMM tile, TK=32, 256 threads, micro 2x4, reg->LDS double buffer.
__device__ __forceinline__ void gemm_tile(
        const float* __restrict__ A, const float* __restrict__ B,
        const float* __restrict__ bias, float* __restrict__ C,
        const int N, const int K, const int relu, const int m0, const int n0,
        LdsGemm* gg) {
    const int tid = threadIdx.x;
    const int tx = tid & 15;
    const int ty = tid >> 4;
    const int ar = tid >> 3;
    const int ac = (tid & 7) * 4;
    const int br = tid >> 3;
    const int bc = (tid & 7) * 8;

    const float* Aptr = A + (size_t)(m0 + ar) * K + ac;
    const float* Bptr = B + (size_t)br * N + n0 + bc;

    {
        const float4 a4  = *(const float4*)Aptr;
        const float4 b40 = *(const float4*)Bptr;
        const float4 b41 = *(const float4*)(Bptr + 4);
        gg->At[0][ac + 0][ar] = a4.x; gg->At[0][ac + 1][ar] = a4.y;
        gg->At[0][ac + 2][ar] = a4.z; gg->At[0][ac + 3][ar] = a4.w;
        *(float4*)&gg->Bs[0][br][bc]     = b40;
        *(float4*)&gg->Bs[0][br][bc + 4] = b41;
    }
    __syncthreads();

    float4 acc0 = {0.f, 0.f, 0.f, 0.f};
    float4 acc1 = {0.f, 0.f, 0.f, 0.f};
    int buf = 0;

    for (int kt = 0; kt < K; kt += 32) {
        const bool has_next = (kt + 32) < K;
        float4 na, nb0, nb1;
        if (has_next) {
            na  = *(const float4*)(Aptr + kt + 32);
            nb0 = *(const float4*)(Bptr + (size_t)(kt + 32) * N);
            nb1 = *(const float4*)(Bptr + (size_t)(kt + 32) * N + 4);
        }
#pragma unroll
        for (int k = 0; k < 32; ++k) {
            const float2 a2 = *(const float2*)&gg->At[buf][k][ty * 2];
            const float4 bv = *(const float4*)&gg->Bs[buf][k][tx * 4];
            acc0.x += a2.x * bv.x; acc0.y += a2.x * bv.y;
            acc0.z += a2.x * bv.z; acc0.w += a2.x * bv.w;
            acc1.x += a2.y * bv.x; acc1.y += a2.y * bv.y;
            acc1.z += a2.y * bv.z; acc1.w += a2.y * bv.w;
        }
        if (has_next) {
            const int nb = buf ^ 1;
            gg->At[nb][ac + 0][ar] = na.x; gg->At[nb][ac + 1][ar] = na.y;
            gg->At[nb][ac + 2][ar] = na.z; gg->At[nb][ac + 3][ar] = na.w;
            *(float4*)&gg->Bs[nb][br][bc]     = nb0;
            *(float4*)&gg->Bs[nb][br][bc + 4] = nb1;
            __syncthreads();
            buf = nb;
        }
    }

    const int col = n0 + tx * 4;
    const int row = m0 + ty * 2;
    const float4 bv = *(const float4*)&bias[col];
    float4 o0, o1;
    o0.x = acc0.x + bv.x; o0.y = acc0.y + bv.y; o0.z = acc0.z + bv.z; o0.w = acc0.w + bv.w;
    o1.x = acc1.x + bv.x; o1.y = acc1.y + bv.y; o1.z = acc1.z + bv.z; o1.w = acc1.w + bv.w;
    if (relu) {
        o0.x = fmaxf(o0.x, 0.f); o0.y = fmaxf(o0.y, 0.f);
        o0.z = fmaxf(o0.z, 0.f); o0.w = fmaxf(o0.w, 0.f);
        o1.x = fmaxf(o1.x, 0.f); o1.y = fmaxf(o1.y, 0.f);
        o1.z = fmaxf(o1.z, 0.f); o1.w = fmaxf(o1.w, 0.f);
    }
    *(float4*)&C[(size_t)row * N + col] = o0;
    *(float4*)&C[(size_t)(row + 1) * N + col] = o1;
}

__device__ __forceinline__ void signal_group(unsigned int* c) {
    __threadfence();
    __syncthreads();
    if (threadIdx.x == 0)
        __hip_atomic_fetch_add(c, 1u, __ATOMIC_RELEASE, __HIP_MEMORY_SCOPE_AGENT);
}

__device__ __forceinline__ void wait_group(unsigned int* c, unsigned int target) {
    if (threadIdx.x == 0)
        while (__hip_atomic_load(c, __ATOMIC_RELAXED, __HIP_MEMORY_SCOPE_AGENT) < target)
            __builtin_amdgcn_s_sleep(2);
    __syncthreads();
    __builtin_amdgcn_fence(__ATOMIC_ACQUIRE, "agent");
}

// Regular (non-cooperative) launch with capacity-safe grid: 512 blocks at
// launch_bounds(256,2) -> 2 blocks/CU guaranteed resident (LDS 2x25KB=50KB,
// VGPR<=256), so every block is placed at t=0 and spin-waits cannot deadlock.
// Phase 1: block b aggregates graphs b and b+512 (8 waves/CU -> HBM-saturated).
// Phase 2: blocks 0..255 run GEMM1 tiles gated on per-group agg counters.
// Phase 3: blocks 0..127 run GEMM2 tiles gated on per-group GEMM1 counters.
__global__ __launch_bounds__(256, 2) void fused_all(
        const float4* __restrict__ nodes,
        const float4* __restrict__ edges,
        const float4* __restrict__ globals_,
        const int* __restrict__ nids,
        const int* __restrict__ eids,
        const float* __restrict__ W1, const float* __restrict__ b1,
        const float* __restrict__ W2, const float* __restrict__ b2,
        float* __restrict__ collected, float* __restrict__ h,
        float* __restrict__ out,
        unsigned int* __restrict__ cnt1, unsigned int* __restrict__ cnt2) {
    __shared__ __align__(16) union { LdsRed red; LdsGemm gg; } lds;

    const int b = blockIdx.x;

    // ---------- phase 1: aggregate graphs b and b+NBLK ----------
    aggregate_one(b, nodes, edges, globals_, nids, eids, collected, &lds.red);
    signal_group(&cnt1[b >> 5]);
    __syncthreads();                       // protect lds.red reuse
    aggregate_one(b + NBLK, nodes, edges, globals_, nids, eids, collected, &lds.red);
    signal_group(&cnt1[(b + NBLK) >> 5]);

    if (b >= G1_BLOCKS) return;

    // ---------- phase 2: GEMM1 tile (h = relu(collected @ W1 + b1)) ----------
    {
        const int mg = b >> 3, ng = b & 7;
        wait_group(&cnt1[mg], GRP);
        gemm_tile(collected, W1, b1, h, DHID, DIN, 1, mg * 32, ng * 64, &lds.gg);
    }
    signal_group(&cnt2[b >> 3]);

    if (b >= G2_BLOCKS) return;

    // ---------- phase 3: GEMM2 tile (out = h @ W2 + b2) ----------
    {
        const int mg = b >> 2, ng = b & 3;
        wait_group(&cnt2[mg], 8u);
        gemm_tile(h, W2, b2, out, DOUT, DHID, 0, mg * 32, ng * 64, &lds.gg);
    }
}

extern "C" void kernel_launch(void* const* d_in, const int* in_sizes, int n_in,
                              void* d_out, int out_size, void* d_ws, size_t ws_size,
                              hipStream_t stream) {
    const float4* nodes    = (const float4*)d_in[0];
    const float4* edges    = (const float4*)d_in[1];
    const float4* globals_ = (const float4*)d_in[2];
    const int*    nids     = (const int*)d_in[3];
    const int*    eids     = (const int*)d_in[4];
    const float*  W1       = (const float*)d_in[5];
    const float*  b1       = (const float*)d_in[6];
    const float*  W2       = (const float*)d_in[7];
    const float*  b2       = (const float*)d_in[8];
    float* out = (float*)d_out;

    float* collected = (float*)d_ws;                 // [G, DIN]  (3 MB), fully written
    float* h         = collected + (size_t)G * DIN;  // [G, DHID] (2 MB), fully written
    unsigned int* cnt1 = (unsigned int*)((char*)d_ws + (size_t)(G * DIN + G * DHID) * sizeof(float));
    unsigned int* cnt2 = cnt1 + NGRP;

    // counters live in ws (re-poisoned 0xAA before every launch) — zero them
    hipMemsetAsync(cnt1, 0, 2 * NGRP * sizeof(unsigned int), stream);

    fused_all<<<NBLK, 256, 0, stream>>>(
        nodes, edges, globals_, nids, eids, W1, b1, W2, b2,
        collected, h, out, cnt1, cnt2);
}

// Round 7
// 463.987 us; speedup vs baseline: 1.4636x; 1.4636x over previous
//
#include <hip/hip_runtime.h>

#define G      1024
#define NNODES 65536
#define NEDGES 262144
#define D      256
#define DIN    768
#define DHID   512
#define DOUT   256

__device__ __forceinline__ int lower_bound(const int* __restrict__ a, int n, int key) {
    int lo = 0, hi = n;
    while (lo < hi) {
        const int mid = (lo + hi) >> 1;
        if (a[mid] < key) lo = mid + 1; else hi = mid;
    }
    return lo;
}

// Precompute segment offsets: eoff[g] = first edge row of graph g (eoff[G]=NEDGES),
// likewise noff. 2050 independent binary searches, latency fully overlapped.
__global__ __launch_bounds__(256) void build_offsets(
        const int* __restrict__ eids, const int* __restrict__ nids,
        int* __restrict__ eoff, int* __restrict__ noff) {
    const int t = blockIdx.x * 256 + threadIdx.x;
    if (t <= G)              eoff[t]         = lower_bound(eids, NEDGES, t);
    else if (t <= 2 * G + 1) noff[t - G - 1] = lower_bound(nids, NNODES, t - G - 1);
}

// One 512-thread block per graph at full occupancy (launch_bounds(512,8) ->
// 32 waves/CU, 4 blocks/CU, LDS 16KB*4=64KB). Each of 8 waves streams rows
// wave, wave+8, ... with 8 float4 loads in flight; LDS-reduce; write
// collected[g] = [edge_agg | node_agg | globals]. No atomics, no id loads.
__global__ __launch_bounds__(512, 8) void fused_agg(
        const float4* __restrict__ nodes,
        const float4* __restrict__ edges,
        const float4* __restrict__ globals_,
        const int* __restrict__ eoff,
        const int* __restrict__ noff,
        float* __restrict__ collected) {
    __shared__ __align__(16) float se[8][D];
    __shared__ __align__(16) float sn[8][D];

    const int g    = blockIdx.x;
    const int lane = threadIdx.x & 63;
    const int wave = threadIdx.x >> 6;

    const int es = eoff[g], ee = eoff[g + 1];
    const int ns = noff[g], ne = noff[g + 1];

    {   // edges
        float4 acc = {0.f, 0.f, 0.f, 0.f};
        int r = es + wave;
        for (; r + 56 < ee; r += 64) {
            const float4* p = edges + (size_t)r * (D / 4) + lane;
            const float4 v0 = p[0 * 8 * (D / 4)];
            const float4 v1 = p[1 * 8 * (D / 4)];
            const float4 v2 = p[2 * 8 * (D / 4)];
            const float4 v3 = p[3 * 8 * (D / 4)];
            const float4 v4 = p[4 * 8 * (D / 4)];
            const float4 v5 = p[5 * 8 * (D / 4)];
            const float4 v6 = p[6 * 8 * (D / 4)];
            const float4 v7 = p[7 * 8 * (D / 4)];
            acc.x += ((v0.x + v1.x) + (v2.x + v3.x)) + ((v4.x + v5.x) + (v6.x + v7.x));
            acc.y += ((v0.y + v1.y) + (v2.y + v3.y)) + ((v4.y + v5.y) + (v6.y + v7.y));
            acc.z += ((v0.z + v1.z) + (v2.z + v3.z)) + ((v4.z + v5.z) + (v6.z + v7.z));
            acc.w += ((v0.w + v1.w) + (v2.w + v3.w)) + ((v4.w + v5.w) + (v6.w + v7.w));
        }
        for (; r < ee; r += 8) {
            const float4 v = edges[(size_t)r * (D / 4) + lane];
            acc.x += v.x; acc.y += v.y; acc.z += v.z; acc.w += v.w;
        }
        *(float4*)&se[wave][lane * 4] = acc;
    }
    {   // nodes
        float4 acc = {0.f, 0.f, 0.f, 0.f};
        int r = ns + wave;
        for (; r + 56 < ne; r += 64) {
            const float4* p = nodes + (size_t)r * (D / 4) + lane;
            const float4 v0 = p[0 * 8 * (D / 4)];
            const float4 v1 = p[1 * 8 * (D / 4)];
            const float4 v2 = p[2 * 8 * (D / 4)];
            const float4 v3 = p[3 * 8 * (D / 4)];
            const float4 v4 = p[4 * 8 * (D / 4)];
            const float4 v5 = p[5 * 8 * (D / 4)];
            const float4 v6 = p[6 * 8 * (D / 4)];
            const float4 v7 = p[7 * 8 * (D / 4)];
            acc.x += ((v0.x + v1.x) + (v2.x + v3.x)) + ((v4.x + v5.x) + (v6.x + v7.x));
            acc.y += ((v0.y + v1.y) + (v2.y + v3.y)) + ((v4.y + v5.y) + (v6.y + v7.y));
            acc.z += ((v0.z + v1.z) + (v2.z + v3.z)) + ((v4.z + v5.z) + (v6.z + v7.z));
            acc.w += ((v0.w + v1.w) + (v2.w + v3.w)) + ((v4.w + v5.w) + (v6.w + v7.w));
        }
        for (; r < ne; r += 8) {
            const float4 v = nodes[(size_t)r * (D / 4) + lane];
            acc.x += v.x; acc.y += v.y; acc.z += v.z; acc.w += v.w;
        }
        *(float4*)&sn[wave][lane * 4] = acc;
    }
    __syncthreads();

    float* row = collected + (size_t)g * DIN;
    if (threadIdx.x < D) {
        const int t = threadIdx.x;
        const float ev = ((se[0][t] + se[1][t]) + (se[2][t] + se[3][t]))
                       + ((se[4][t] + se[5][t]) + (se[6][t] + se[7][t]));
        row[t]         = ev;
        row[2 * D + t] = ((const float*)globals_)[(size_t)g * D + t];
    } else {
        const int t = threadIdx.x - D;
        const float nv = ((sn[0][t] + sn[1][t]) + (sn[2][t] + sn[3][t]))
                       + ((sn[4][t] + sn[5][t]) + (sn[6][t] + sn[7][t]));
        row[D + t] = nv;
    }
}

// fp32 GEMM, C[M,N]=act(A@B+bias): tile 32x64, TK=32, 256 threads, micro 2x4,
// k-major A in LDS (+2 pad), reg->LDS double buffer, one barrier per K-tile.
template <int TM, int TN, int TK>
__global__ __launch_bounds__(256) void gemm_bias_act(
        const float* __restrict__ A, const float* __restrict__ B,
        const float* __restrict__ bias, float* __restrict__ C,
        int M, int N, int K, int relu) {
    __shared__ float At[2][TK][TM + 2];
    __shared__ __align__(16) float Bs[2][TK][TN];

    const int tid = threadIdx.x;
    const int tx = tid & 15;
    const int ty = tid >> 4;
    const int m0 = blockIdx.y * TM;
    const int n0 = blockIdx.x * TN;

    const int ar = tid >> 3;
    const int ac = (tid & 7) * 4;
    const int br = tid >> 3;
    const int bc = (tid & 7) * 8;

    const float* Aptr = A + (size_t)(m0 + ar) * K + ac;
    const float* Bptr = B + (size_t)br * N + n0 + bc;

    {
        const float4 a4  = *(const float4*)Aptr;
        const float4 b40 = *(const float4*)Bptr;
        const float4 b41 = *(const float4*)(Bptr + 4);
        At[0][ac + 0][ar] = a4.x; At[0][ac + 1][ar] = a4.y;
        At[0][ac + 2][ar] = a4.z; At[0][ac + 3][ar] = a4.w;
        *(float4*)&Bs[0][br][bc]     = b40;
        *(float4*)&Bs[0][br][bc + 4] = b41;
    }
    __syncthreads();

    float4 acc0 = {0.f, 0.f, 0.f, 0.f};
    float4 acc1 = {0.f, 0.f, 0.f, 0.f};
    int buf = 0;

    for (int kt = 0; kt < K; kt += TK) {
        const bool has_next = (kt + TK) < K;
        float4 na, nb0, nb1;
        if (has_next) {
            na  = *(const float4*)(Aptr + kt + TK);
            nb0 = *(const float4*)(Bptr + (size_t)(kt + TK) * N);
            nb1 = *(const float4*)(Bptr + (size_t)(kt + TK) * N + 4);
        }
#pragma unroll
        for (int k = 0; k < TK; ++k) {
            const float2 a2 = *(const float2*)&At[buf][k][ty * 2];
            const float4 bv = *(const float4*)&Bs[buf][k][tx * 4];
            acc0.x += a2.x * bv.x; acc0.y += a2.x * bv.y;
            acc0.z += a2.x * bv.z; acc0.w += a2.x * bv.w;
            acc1.x += a2.y * bv.x; acc1.y += a2.y * bv.y;
            acc1.z += a2.y * bv.z; acc1.w += a2.y * bv.w;
        }
        if (has_next) {
            const int nb = buf ^ 1;
            At[nb][ac + 0][ar] = na.x; At[nb][ac + 1][ar] = na.y;
            At[nb][ac + 2][ar] = na.z; At[nb][ac + 3][ar] = na.w;
            *(float4*)&Bs[nb][br][bc]     = nb0;
            *(float4*)&Bs[nb][br][bc + 4] = nb1;
            __syncthreads();
            buf = nb;
        }
    }

    const int col = n0 + tx * 4;
    const int row = m0 + ty * 2;
    const float4 bv = *(const float4*)&bias[col];
    float4 o0, o1;
    o0.x = acc0.x + bv.x; o0.y = acc0.y + bv.y; o0.z = acc0.z + bv.z; o0.w = acc0.w + bv.w;
    o1.x = acc1.x + bv.x; o1.y = acc1.y + bv.y; o1.z = acc1.z + bv.z; o1.w = acc1.w + bv.w;
    if (relu) {
        o0.x = fmaxf(o0.x, 0.f); o0.y = fmaxf(o0.y, 0.f);
        o0.z = fmaxf(o0.z, 0.f); o0.w = fmaxf(o0.w, 0.f);
        o1.x = fmaxf(o1.x, 0.f); o1.y = fmaxf(o1.y, 0.f);
        o1.z = fmaxf(o1.z, 0.f); o1.w = fmaxf(o1.w, 0.f);
    }
    *(float4*)&C[(size_t)row * N + col] = o0;
    *(float4*)&C[(size_t)(row + 1) * N + col] = o1;
}

extern "C" void kernel_launch(void* const* d_in, const int* in_sizes, int n_in,
                              void* d_out, int out_size, void* d_ws, size_t ws_size,
                              hipStream_t stream) {
    const float* nodes    = (const float*)d_in[0];
    const float* edges    = (const float*)d_in[1];
    const float* globals_ = (const float*)d_in[2];
    const int*   nids     = (const int*)d_in[3];
    const int*   eids     = (const int*)d_in[4];
    const float* W1       = (const float*)d_in[5];
    const float* b1       = (const float*)d_in[6];
    const float* W2       = (const float*)d_in[7];
    const float* b2       = (const float*)d_in[8];
    float* out = (float*)d_out;

    float* collected = (float*)d_ws;                 // [G, DIN]  (3 MB), fully written
    float* h         = collected + (size_t)G * DIN;  // [G, DHID] (2 MB), fully written
    int*   eoff      = (int*)(h + (size_t)G * DHID); // [G+1]
    int*   noff      = eoff + (G + 1);               // [G+1]

    build_offsets<<<(2 * (G + 1) + 255) / 256, 256, 0, stream>>>(eids, nids, eoff, noff);

    fused_agg<<<G, 512, 0, stream>>>(
        (const float4*)nodes, (const float4*)edges, (const float4*)globals_,
        eoff, noff, collected);

    gemm_bias_act<32, 64, 32><<<dim3(DHID / 64, G / 32), 256, 0, stream>>>(
        collected, W1, b1, h, G, DHID, DIN, 1);

    gemm_bias_act<32, 64, 32><<<dim3(DOUT / 64, G / 32), 256, 0, stream>>>(
        h, W2, b2, out, G, DOUT, DHID, 0);
}

// Round 8
// 456.032 us; speedup vs baseline: 1.4891x; 1.0174x over previous
//
#include <hip/hip_runtime.h>

#define G      1024
#define NNODES 65536
#define NEDGES 262144
#define D      256
#define DIN    768
#define DHID   512
#define DOUT   256
#define CW     512            // collected row width: [edge_agg | node_agg]

#define AGG_BLOCKS 1024       // x 4 waves = 4096 waves
#define EROWS      64         // edge rows per wave  (4096*64 = 262144)
#define NROWS      16         // node rows per wave  (4096*16 = 65536)

__device__ __forceinline__ void flush_acc(float* __restrict__ dst, int cur, int col,
                                          float4& acc) {
    float* p = dst + (size_t)cur * CW + col;
    atomicAdd(p + 0, acc.x); atomicAdd(p + 1, acc.y);
    atomicAdd(p + 2, acc.z); atomicAdd(p + 3, acc.w);
    acc.x = acc.y = acc.z = acc.w = 0.f;
}

__device__ __forceinline__ void row_step(int id, const float4 v, int& cur, float4& acc,
                                         float* __restrict__ dst, int col) {
    if (id != cur) { flush_acc(dst, cur, col, acc); cur = id; }
    acc.x += v.x; acc.y += v.y; acc.z += v.z; acc.w += v.w;
}

// Load one 8-row group: 8 KiB contiguous (rows r..r+7, lane covers 16 B of each
// row) + the 8 ids. All 10 loads are independent — issued as one burst.
__device__ __forceinline__ void load_group(const float4* __restrict__ src,
                                           const int* __restrict__ ids, int r, int lane,
                                           float4 v[8], int4& i0, int4& i1) {
    const float4* p = src + (size_t)r * (D / 4) + lane;
#pragma unroll
    for (int j = 0; j < 8; ++j) v[j] = p[j * (D / 4)];
    i0 = *(const int4*)&ids[r];
    i1 = *(const int4*)&ids[r + 4];
}

__device__ __forceinline__ void proc_group(const float4 v[8], int4 i0, int4 i1,
                                           int& cur, float4& acc,
                                           float* __restrict__ dst, int col) {
    if (i0.x == cur && i1.w == cur) {   // whole group inside current run (common)
        acc.x += ((v[0].x + v[1].x) + (v[2].x + v[3].x)) + ((v[4].x + v[5].x) + (v[6].x + v[7].x));
        acc.y += ((v[0].y + v[1].y) + (v[2].y + v[3].y)) + ((v[4].y + v[5].y) + (v[6].y + v[7].y));
        acc.z += ((v[0].z + v[1].z) + (v[2].z + v[3].z)) + ((v[4].z + v[5].z) + (v[6].z + v[7].z));
        acc.w += ((v[0].w + v[1].w) + (v[2].w + v[3].w)) + ((v[4].w + v[5].w) + (v[6].w + v[7].w));
    } else {                            // run boundary inside the group
        row_step(i0.x, v[0], cur, acc, dst, col);
        row_step(i0.y, v[1], cur, acc, dst, col);
        row_step(i0.z, v[2], cur, acc, dst, col);
        row_step(i0.w, v[3], cur, acc, dst, col);
        row_step(i1.x, v[4], cur, acc, dst, col);
        row_step(i1.y, v[5], cur, acc, dst, col);
        row_step(i1.z, v[6], cur, acc, dst, col);
        row_step(i1.w, v[7], cur, acc, dst, col);
    }
}

// Sorted-segment sum with register ping-pong pipeline: group k+1's loads are
// issued before group k's accumulate, so ~8-16 KiB stays in flight per wave at
// all times (no vmcnt(0) drain in steady state). Flush via atomicAdd only at
// run boundaries (~1.25 per wave on average).
__device__ __forceinline__ void seg_sum_pipelined(
        const float4* __restrict__ src, const int* __restrict__ ids,
        float* __restrict__ dst, int col, int r, int ngroups, int lane) {
    float4 va[8], vb[8];
    int4 ia0, ia1, ib0, ib1;
    float4 acc = {0.f, 0.f, 0.f, 0.f};
    int cur = ids[r];

    load_group(src, ids, r, lane, va, ia0, ia1);
    for (int gpair = 0; gpair < ngroups / 2 - 1; ++gpair) {
        load_group(src, ids, r + 8, lane, vb, ib0, ib1);
        proc_group(va, ia0, ia1, cur, acc, dst, col);
        r += 8;
        load_group(src, ids, r + 8, lane, va, ia0, ia1);
        proc_group(vb, ib0, ib1, cur, acc, dst, col);
        r += 8;
    }
    load_group(src, ids, r + 8, lane, vb, ib0, ib1);
    proc_group(va, ia0, ia1, cur, acc, dst, col);
    proc_group(vb, ib0, ib1, cur, acc, dst, col);
    flush_acc(dst, cur, col, acc);
}

// 1024 blocks x 256 thr, launch_bounds(256,4) -> 16 waves/CU, no LDS.
// Wave W: edge rows [W*64, +64) then node rows [W*16, +16), contiguous.
__global__ __launch_bounds__(256, 4) void fused_agg(
        const float4* __restrict__ nodes,
        const float4* __restrict__ edges,
        const int* __restrict__ nids,
        const int* __restrict__ eids,
        float* __restrict__ collected) {
    const int lane = threadIdx.x & 63;
    const int wave = threadIdx.x >> 6;
    const int W    = blockIdx.x * 4 + wave;         // 0..4095

    seg_sum_pipelined(edges, eids, collected, lane * 4,       W * EROWS, EROWS / 8, lane);
    seg_sum_pipelined(nodes, nids, collected, D + lane * 4,   W * NROWS, NROWS / 8, lane);
}

// fp32 GEMM: C[M,N]=act(A@B+bias), tile 32x64, TK=32, 256 thr, micro 2x4,
// k-major A in LDS (+2 pad), reg->LDS double buffer, one barrier per K-tile.
// A is split across two sources: cols [0,asplit) from A1 (stride s1), cols
// [asplit,K) from A2 (stride s2) — lets GEMM1 read globals_ in place.
__global__ __launch_bounds__(256) void gemm_bias_act(
        const float* __restrict__ A1, const float* __restrict__ A2,
        const float* __restrict__ B,
        const float* __restrict__ bias, float* __restrict__ C,
        int N, int K, int asplit, int s1, int s2, int relu) {
    __shared__ float At[2][32][34];
    __shared__ __align__(16) float Bs[2][32][64];

    const int tid = threadIdx.x;
    const int tx = tid & 15;
    const int ty = tid >> 4;
    const int m0 = blockIdx.y * 32;
    const int n0 = blockIdx.x * 64;

    const int ar = tid >> 3;
    const int ac = (tid & 7) * 4;
    const int br = tid >> 3;
    const int bc = (tid & 7) * 8;

    const int arow = m0 + ar;
    const float* Bptr = B + (size_t)br * N + n0 + bc;

    auto loadA = [&](int kc) -> float4 {
        return (kc < asplit) ? *(const float4*)&A1[(size_t)arow * s1 + kc + ac]
                             : *(const float4*)&A2[(size_t)arow * s2 + (kc - asplit) + ac];
    };

    {
        const float4 a4  = loadA(0);
        const float4 b40 = *(const float4*)Bptr;
        const float4 b41 = *(const float4*)(Bptr + 4);
        At[0][ac + 0][ar] = a4.x; At[0][ac + 1][ar] = a4.y;
        At[0][ac + 2][ar] = a4.z; At[0][ac + 3][ar] = a4.w;
        *(float4*)&Bs[0][br][bc]     = b40;
        *(float4*)&Bs[0][br][bc + 4] = b41;
    }
    __syncthreads();

    float4 acc0 = {0.f, 0.f, 0.f, 0.f};
    float4 acc1 = {0.f, 0.f, 0.f, 0.f};
    int buf = 0;

    for (int kt = 0; kt < K; kt += 32) {
        const bool has_next = (kt + 32) < K;
        float4 na, nb0, nb1;
        if (has_next) {
            na  = loadA(kt + 32);
            nb0 = *(const float4*)(Bptr + (size_t)(kt + 32) * N);
            nb1 = *(const float4*)(Bptr + (size_t)(kt + 32) * N + 4);
        }
#pragma unroll
        for (int k = 0; k < 32; ++k) {
            const float2 a2 = *(const float2*)&At[buf][k][ty * 2];
            const float4 bv = *(const float4*)&Bs[buf][k][tx * 4];
            acc0.x += a2.x * bv.x; acc0.y += a2.x * bv.y;
            acc0.z += a2.x * bv.z; acc0.w += a2.x * bv.w;
            acc1.x += a2.y * bv.x; acc1.y += a2.y * bv.y;
            acc1.z += a2.y * bv.z; acc1.w += a2.y * bv.w;
        }
        if (has_next) {
            const int nb = buf ^ 1;
            At[nb][ac + 0][ar] = na.x; At[nb][ac + 1][ar] = na.y;
            At[nb][ac + 2][ar] = na.z; At[nb][ac + 3][ar] = na.w;
            *(float4*)&Bs[nb][br][bc]     = nb0;
            *(float4*)&Bs[nb][br][bc + 4] = nb1;
            __syncthreads();
            buf = nb;
        }
    }

    const int col = n0 + tx * 4;
    const int row = m0 + ty * 2;
    const float4 bv = *(const float4*)&bias[col];
    float4 o0, o1;
    o0.x = acc0.x + bv.x; o0.y = acc0.y + bv.y; o0.z = acc0.z + bv.z; o0.w = acc0.w + bv.w;
    o1.x = acc1.x + bv.x; o1.y = acc1.y + bv.y; o1.z = acc1.z + bv.z; o1.w = acc1.w + bv.w;
    if (relu) {
        o0.x = fmaxf(o0.x, 0.f); o0.y = fmaxf(o0.y, 0.f);
        o0.z = fmaxf(o0.z, 0.f); o0.w = fmaxf(o0.w, 0.f);
        o1.x = fmaxf(o1.x, 0.f); o1.y = fmaxf(o1.y, 0.f);
        o1.z = fmaxf(o1.z, 0.f); o1.w = fmaxf(o1.w, 0.f);
    }
    *(float4*)&C[(size_t)row * N + col] = o0;
    *(float4*)&C[(size_t)(row + 1) * N + col] = o1;
}

extern "C" void kernel_launch(void* const* d_in, const int* in_sizes, int n_in,
                              void* d_out, int out_size, void* d_ws, size_t ws_size,
                              hipStream_t stream) {
    const float* nodes    = (const float*)d_in[0];
    const float* edges    = (const float*)d_in[1];
    const float* globals_ = (const float*)d_in[2];
    const int*   nids     = (const int*)d_in[3];
    const int*   eids     = (const int*)d_in[4];
    const float* W1       = (const float*)d_in[5];
    const float* b1       = (const float*)d_in[6];
    const float* W2       = (const float*)d_in[7];
    const float* b2       = (const float*)d_in[8];
    float* out = (float*)d_out;

    float* collected = (float*)d_ws;                 // [G, 512] (2 MB), atomic-accumulated
    float* h         = collected + (size_t)G * CW;   // [G, DHID] (2 MB), fully written

    // zero the accumulator buffer (ws re-poisoned 0xAA before every launch)
    hipMemsetAsync(collected, 0, (size_t)G * CW * sizeof(float), stream);

    fused_agg<<<AGG_BLOCKS, 256, 0, stream>>>(
        (const float4*)nodes, (const float4*)edges, nids, eids, collected);

    // GEMM1: A = [collected | globals_] (K=768 split at 512), relu
    gemm_bias_act<<<dim3(DHID / 64, G / 32), 256, 0, stream>>>(
        collected, globals_, W1, b1, h, DHID, DIN, CW, CW, D, 1);

    // GEMM2: A = h (K=512, no split), no relu
    gemm_bias_act<<<dim3(DOUT / 64, G / 32), 256, 0, stream>>>(
        h, h, W2, b2, out, DOUT, DHID, DHID, DHID, DHID, 0);
}